// Round 5
// baseline (157.310 us; speedup 1.0000x reference)
//
#include <hip/hip_runtime.h>
#include <hip/hip_cooperative_groups.h>

namespace cg = cooperative_groups;

#define FD 768
#define HD 256
#define NF 512
#define NC 512
#define PAIRS (NF * (NF - 1) / 2)   // 130816
#define NS 16                       // split-k slices
#define KS 48                       // k per slice (one staging round)
#define EPITCH 132                  // floats: transposed E row (128 rows + 4 pad)
#define WPITCH 33                   // float4s: Ws row (128 cols + 4 pad floats)

// ---------------------------------------------------------------------------
// ONE cooperative kernel, 256 blocks x 256 threads (1+ block/CU, co-resident).
// Phase A: GEMM partials — 16 tiles (128x128) x 16 k-slices, 8x8-equiv
//          microtile (rows 8ty..+7, cols {4tx..+3, 64+4tx..+3}).
//          E staged TRANSPOSED (Et[k][row]) so a-reads hit 4 distinct
//          bank-quads; Ws pitch 33 f4 so w-reads are 2 addrs/quad.
// Phase B: reduce 16 partials + b1 -> C (one float4 per thread).
// Phase C: pair scores, 528 16x16 tiles grid-strided over 256 blocks.
// grid.sync() between phases replaces kernel boundaries (+L2 flush cost).
// ---------------------------------------------------------------------------
__global__ __launch_bounds__(256) void fused_kernel(
    const float* __restrict__ E, const float* __restrict__ W1,
    const float* __restrict__ b1, const float* __restrict__ W2,
    const float* __restrict__ b2, float* __restrict__ out,
    float* __restrict__ ws)
{
    __shared__ float smem[KS * EPITCH + KS * WPITCH * 4];   // 50.7 KB
    __shared__ float w2s[HD];
    float*  Et  = smem;                               // [48][132] floats
    float4* Ws4 = (float4*)(smem + KS * EPITCH);      // [48][33] float4

    const int tid = threadIdx.x;
    const int bid = blockIdx.x;
    const int tx = tid & 15, ty = tid >> 4;

    float* part = ws;                                 // [16][512][512]
    float* C    = ws + (size_t)NS * NF * NC;          // [512][512]
    float4* C4  = (float4*)C;

    w2s[tid] = W2[tid];

    // ================= Phase A: GEMM partials =================
    {
        const int tile = bid >> 4, z = bid & 15;
        const int rt = tile >> 2, ct = tile & 3;
        const int r0 = rt * 128, c0g = ct * 128;
        const int c0w4 = (c0g & 255) >> 2;            // f4 col offset in W half
        const int dofs = (c0g >= 256) ? FD : 0;
        const int dbase = z * KS;

        // stage E transposed: 128 rows x 12 f4 -> Et[k][r]
        const float4* E4 = (const float4*)E;          // row pitch 192 f4
        #pragma unroll
        for (int s = 0; s < 6; ++s) {
            int e = s * 256 + tid;
            int r = e / 12, kq = e - 12 * r;
            float4 v = E4[(size_t)(r0 + r) * 192 + z * 12 + kq];
            Et[(4 * kq + 0) * EPITCH + r] = v.x;
            Et[(4 * kq + 1) * EPITCH + r] = v.y;
            Et[(4 * kq + 2) * EPITCH + r] = v.z;
            Et[(4 * kq + 3) * EPITCH + r] = v.w;
        }
        // stage W: 48 k-rows x 32 f4
        const float4* W14 = (const float4*)W1;        // row pitch 64 f4
        #pragma unroll
        for (int s = 0; s < 6; ++s) {
            int e = s * 256 + tid;
            int wr = e >> 5, wc = e & 31;
            Ws4[wr * WPITCH + wc] = W14[(size_t)(dofs + dbase + wr) * 64 + c0w4 + wc];
        }
        __syncthreads();

        float4 accL[8] = {}; float4 accH[8] = {};
        #pragma unroll
        for (int kq = 0; kq < KS / 4; ++kq) {
            #pragma unroll
            for (int kk = 0; kk < 4; ++kk) {
                const int k = 4 * kq + kk;
                float4 aL = *(const float4*)&Et[k * EPITCH + 8 * ty];
                float4 aH = *(const float4*)&Et[k * EPITCH + 8 * ty + 4];
                float4 wL = Ws4[k * WPITCH + tx];
                float4 wH = Ws4[k * WPITCH + tx + 16];
                const float av[8] = {aL.x, aL.y, aL.z, aL.w, aH.x, aH.y, aH.z, aH.w};
                #pragma unroll
                for (int i = 0; i < 8; ++i) {
                    accL[i].x = fmaf(av[i], wL.x, accL[i].x);
                    accL[i].y = fmaf(av[i], wL.y, accL[i].y);
                    accL[i].z = fmaf(av[i], wL.z, accL[i].z);
                    accL[i].w = fmaf(av[i], wL.w, accL[i].w);
                    accH[i].x = fmaf(av[i], wH.x, accH[i].x);
                    accH[i].y = fmaf(av[i], wH.y, accH[i].y);
                    accH[i].z = fmaf(av[i], wH.z, accH[i].z);
                    accH[i].w = fmaf(av[i], wH.w, accH[i].w);
                }
            }
        }

        float* dst = part + (size_t)z * NF * NC + (size_t)(r0 + 8 * ty) * NC + c0g + 4 * tx;
        #pragma unroll
        for (int i = 0; i < 8; ++i) {
            *(float4*)&dst[i * NC]      = accL[i];
            *(float4*)&dst[i * NC + 64] = accH[i];
        }
    }

    __threadfence();
    cg::this_grid().sync();

    // ================= Phase B: reduce partials + b1 =================
    {
        const int gid = bid * 256 + tid;              // 0..65535, one f4 each
        const float4* p4 = (const float4*)part;
        float4 s = p4[gid];
        #pragma unroll
        for (int zz = 1; zz < NS; ++zz) {
            float4 v = p4[(size_t)zz * (NF * NC / 4) + gid];
            s.x += v.x; s.y += v.y; s.z += v.z; s.w += v.w;
        }
        const int c4 = gid & 127;
        if (c4 < 64) {
            float4 b = ((const float4*)b1)[c4];
            s.x += b.x; s.y += b.y; s.z += b.z; s.w += b.w;
        }
        C4[gid] = s;
    }

    __threadfence();
    cg::this_grid().sync();

    // ================= Phase C: pair scores =================
    {
        float4* As = (float4*)smem;          // [16][65]
        float4* Bs = As + 16 * 65;           // [16][65]
        const float bias2 = b2[0];

        for (int t = bid; t < 528; t += 256) {
            int rem = t, bi = 0;
            while (rem >= 32 - bi) { rem -= 32 - bi; ++bi; }
            const int bj = bi + rem;
            const int i0 = bi * 16, j0 = bj * 16;

            if (t != bid) __syncthreads();   // protect LDS from previous tile
            #pragma unroll
            for (int s = 0; s < 4; ++s) {
                int e = s * 256 + tid;
                int row = e >> 6, c4 = e & 63;
                As[row * 65 + c4] = C4[(i0 + row) * 128 + c4];
                Bs[row * 65 + c4] = C4[(j0 + row) * 128 + 64 + c4];
            }
            __syncthreads();

            float acc = 0.f;
            #pragma unroll 8
            for (int k4 = 0; k4 < HD / 4; ++k4) {
                float4 a = As[ty * 65 + k4];
                float4 b = Bs[tx * 65 + k4];
                float4 w = ((float4*)w2s)[k4];
                acc = fmaf(fmaxf(a.x + b.x, 0.f), w.x, acc);
                acc = fmaf(fmaxf(a.y + b.y, 0.f), w.y, acc);
                acc = fmaf(fmaxf(a.z + b.z, 0.f), w.z, acc);
                acc = fmaf(fmaxf(a.w + b.w, 0.f), w.w, acc);
            }

            const int i = i0 + ty, j = j0 + tx;
            if (j > i) {
                const int p = i * (2 * NF - i - 1) / 2 + (j - i - 1);
                out[p]             = (float)i;
                out[PAIRS + p]     = (float)j;
                out[2 * PAIRS + p] = acc + bias2;
            }
        }
    }
}

extern "C" void kernel_launch(void* const* d_in, const int* in_sizes, int n_in,
                              void* d_out, int out_size, void* d_ws, size_t ws_size,
                              hipStream_t stream) {
    const float* E  = (const float*)d_in[0];
    const float* W1 = (const float*)d_in[1];
    const float* b1 = (const float*)d_in[2];
    const float* W2 = (const float*)d_in[3];
    const float* b2 = (const float*)d_in[4];
    float* out = (float*)d_out;
    float* ws  = (float*)d_ws;

    void* args[] = {(void*)&E, (void*)&W1, (void*)&b1, (void*)&W2,
                    (void*)&b2, (void*)&out, (void*)&ws};
    hipLaunchCooperativeKernel((void*)fused_kernel, dim3(256), dim3(256),
                               args, 0, stream);
}

// Round 6
// 34.637 us; speedup vs baseline: 4.5416x; 4.5416x over previous
//
#include <hip/hip_runtime.h>

#define FD 768
#define HD 256
#define NF 512
#define NC 512
#define PAIRS (NF * (NF - 1) / 2)   // 130816
#define NS 16                       // split-k slices
#define KS 48                       // k per slice (one staging round)
#define EPITCH 132                  // floats: transposed-E row pitch (128 + 4 pad)
#define WPITCH 33                   // float4s: Ws row pitch (32 + 1 pad)

// ---------------------------------------------------------------------------
// Kernel 1: split-K GEMM, 128x128 tile, 8x8 microtile, ONE staging round.
//   part[z][r][c] = sum_{d in slice z} E[r][d] * Wcat[d][c]
// Grid (4,4,16) = 256 blocks. E staged TRANSPOSED (Et[k][row]): a-reads are
// float4 on 8 distinct bank-quads; Ws pitch 33 f4: w-reads 2 addrs/quad.
// Per k: 4 b128 feed 64 FMA -> VALU/LDS balanced (~3 us).
// ---------------------------------------------------------------------------
__global__ __launch_bounds__(256) void gemm_kernel(
    const float* __restrict__ E, const float* __restrict__ W1,
    float* __restrict__ part)
{
    __shared__ float smem[KS * EPITCH + KS * WPITCH * 4];   // 50.7 KB
    float*  Et  = smem;                               // [48][132] floats
    float4* Ws4 = (float4*)(smem + KS * EPITCH);      // [48][33] float4

    const int tid = threadIdx.x;
    const int tx = tid & 15, ty = tid >> 4;
    const int bx = blockIdx.x, by = blockIdx.y, z = blockIdx.z;
    const int r0 = by * 128, c0g = bx * 128;
    const int c0w4 = (c0g & 255) >> 2;
    const int dofs = (c0g >= 256) ? FD : 0;
    const int dbase = z * KS;

    // stage E transposed: 128 rows x 12 f4 -> Et[k][r]
    const float4* E4 = (const float4*)E;              // row pitch 192 f4
    #pragma unroll
    for (int s = 0; s < 6; ++s) {
        int e = s * 256 + tid;
        int r = e / 12, kq = e - 12 * r;
        float4 v = E4[(size_t)(r0 + r) * 192 + z * 12 + kq];
        Et[(4 * kq + 0) * EPITCH + r] = v.x;
        Et[(4 * kq + 1) * EPITCH + r] = v.y;
        Et[(4 * kq + 2) * EPITCH + r] = v.z;
        Et[(4 * kq + 3) * EPITCH + r] = v.w;
    }
    // stage W: 48 k-rows x 32 f4
    const float4* W14 = (const float4*)W1;            // row pitch 64 f4
    #pragma unroll
    for (int s = 0; s < 6; ++s) {
        int e = s * 256 + tid;
        int wr = e >> 5, wc = e & 31;
        Ws4[wr * WPITCH + wc] = W14[(size_t)(dofs + dbase + wr) * 64 + c0w4 + wc];
    }
    __syncthreads();

    float4 accL[8] = {}; float4 accH[8] = {};
    #pragma unroll
    for (int kq = 0; kq < KS / 4; ++kq) {
        #pragma unroll
        for (int kk = 0; kk < 4; ++kk) {
            const int k = 4 * kq + kk;
            float4 aL = *(const float4*)&Et[k * EPITCH + 8 * ty];
            float4 aH = *(const float4*)&Et[k * EPITCH + 8 * ty + 4];
            float4 wL = Ws4[k * WPITCH + tx];
            float4 wH = Ws4[k * WPITCH + tx + 16];
            const float av[8] = {aL.x, aL.y, aL.z, aL.w, aH.x, aH.y, aH.z, aH.w};
            #pragma unroll
            for (int i = 0; i < 8; ++i) {
                accL[i].x = fmaf(av[i], wL.x, accL[i].x);
                accL[i].y = fmaf(av[i], wL.y, accL[i].y);
                accL[i].z = fmaf(av[i], wL.z, accL[i].z);
                accL[i].w = fmaf(av[i], wL.w, accL[i].w);
                accH[i].x = fmaf(av[i], wH.x, accH[i].x);
                accH[i].y = fmaf(av[i], wH.y, accH[i].y);
                accH[i].z = fmaf(av[i], wH.z, accH[i].z);
                accH[i].w = fmaf(av[i], wH.w, accH[i].w);
            }
        }
    }

    float* dst = part + (size_t)z * NF * NC + (size_t)(r0 + 8 * ty) * NC + c0g + 4 * tx;
    #pragma unroll
    for (int i = 0; i < 8; ++i) {
        *(float4*)&dst[i * NC]      = accL[i];
        *(float4*)&dst[i * NC + 64] = accH[i];
    }
}

// ---------------------------------------------------------------------------
// Kernel 2: C = sum_z part[z] (+ b1 on left half). 256 blocks x 256 thr.
// ---------------------------------------------------------------------------
__global__ __launch_bounds__(256) void reduce_kernel(
    const float* __restrict__ part, const float* __restrict__ b1,
    float* __restrict__ C)
{
    const int idx = blockIdx.x * 256 + threadIdx.x;   // f4 index, 0..65535
    const float4* p4 = (const float4*)part;
    float4 s = p4[idx];
    #pragma unroll
    for (int z = 1; z < NS; ++z) {
        float4 v = p4[(size_t)z * (NF * NC / 4) + idx];
        s.x += v.x; s.y += v.y; s.z += v.z; s.w += v.w;
    }
    const int c4 = idx & 127;
    if (c4 < 64) {
        float4 b = ((const float4*)b1)[c4];
        s.x += b.x; s.y += b.y; s.z += b.z; s.w += b.w;
    }
    ((float4*)C)[idx] = s;
}

// ---------------------------------------------------------------------------
// Kernel 3: pair scores. 32x32 pair tile per block (136 triangular blocks),
// 2x2 microtile (4 pairs/thread): 5 b128 per 16 pair-k -> VALU-bound.
// LDS float4[32][64] with k4 XOR swizzle key (row>>1)&7 (conflict-free).
// ---------------------------------------------------------------------------
__global__ __launch_bounds__(256) void pair_kernel(
    const float* __restrict__ C, const float* __restrict__ W2,
    const float* __restrict__ b2, float* __restrict__ out)
{
    __shared__ float4 As[32 * 64];
    __shared__ float4 Bs[32 * 64];
    __shared__ float4 w2s[HD / 4];

    int rem = blockIdx.x, bi = 0;
    while (rem >= 16 - bi) { rem -= 16 - bi; ++bi; }
    const int bj = bi + rem;
    const int i0 = bi * 32, j0 = bj * 32;

    const int tid = threadIdx.x;
    ((float*)w2s)[tid] = W2[tid];

    const float4* C4 = (const float4*)C;   // row pitch 128 f4
    #pragma unroll
    for (int s = 0; s < 8; ++s) {
        int e = tid + 256 * s;
        int row = e >> 6, c4 = e & 63;
        int sc4 = c4 ^ ((row >> 1) & 7);
        As[row * 64 + sc4] = C4[(i0 + row) * 128 + c4];        // A half
        Bs[row * 64 + sc4] = C4[(j0 + row) * 128 + 64 + c4];   // B half
    }
    __syncthreads();

    const int tx = tid & 15, ty = tid >> 4;
    const int ka = ty & 7, kb = tx & 7;
    float acc00 = 0.f, acc01 = 0.f, acc10 = 0.f, acc11 = 0.f;

    #pragma unroll 8
    for (int k4 = 0; k4 < HD / 4; ++k4) {
        float4 a0 = As[(2 * ty + 0) * 64 + (k4 ^ ka)];
        float4 a1 = As[(2 * ty + 1) * 64 + (k4 ^ ka)];
        float4 b0 = Bs[(2 * tx + 0) * 64 + (k4 ^ kb)];
        float4 b1v = Bs[(2 * tx + 1) * 64 + (k4 ^ kb)];
        float4 w = w2s[k4];
        #define PACC(ACC, A, B) \
            ACC = fmaf(fmaxf(A.x + B.x, 0.f), w.x, ACC); \
            ACC = fmaf(fmaxf(A.y + B.y, 0.f), w.y, ACC); \
            ACC = fmaf(fmaxf(A.z + B.z, 0.f), w.z, ACC); \
            ACC = fmaf(fmaxf(A.w + B.w, 0.f), w.w, ACC);
        PACC(acc00, a0, b0) PACC(acc01, a0, b1v)
        PACC(acc10, a1, b0) PACC(acc11, a1, b1v)
        #undef PACC
    }

    const float bias2 = b2[0];
    #pragma unroll
    for (int u = 0; u < 4; ++u) {
        int i = i0 + 2 * ty + (u >> 1);
        int j = j0 + 2 * tx + (u & 1);
        float v = (u == 0) ? acc00 : (u == 1) ? acc01 : (u == 2) ? acc10 : acc11;
        if (j > i) {
            int p = i * (2 * NF - i - 1) / 2 + (j - i - 1);
            out[p]             = (float)i;
            out[PAIRS + p]     = (float)j;
            out[2 * PAIRS + p] = v + bias2;
        }
    }
}

extern "C" void kernel_launch(void* const* d_in, const int* in_sizes, int n_in,
                              void* d_out, int out_size, void* d_ws, size_t ws_size,
                              hipStream_t stream) {
    const float* E  = (const float*)d_in[0];
    const float* W1 = (const float*)d_in[1];
    const float* b1 = (const float*)d_in[2];
    const float* W2 = (const float*)d_in[3];
    const float* b2 = (const float*)d_in[4];
    float* out  = (float*)d_out;
    float* part = (float*)d_ws;                            // 16 MiB partials
    float* C    = (float*)d_ws + (size_t)NS * NF * NC;     // 1 MiB reduced C

    gemm_kernel<<<dim3(4, 4, NS), 256, 0, stream>>>(E, W1, part);
    reduce_kernel<<<NF * NC / 4 / 256, 256, 0, stream>>>(part, b1, C);
    pair_kernel<<<136, 256, 0, stream>>>(C, W2, b2, out);
}

// Round 7
// 27.488 us; speedup vs baseline: 5.7228x; 1.2601x over previous
//
#include <hip/hip_runtime.h>

#define FD 768
#define HD 256
#define NF 512
#define NC 512
#define PAIRS (NF * (NF - 1) / 2)   // 130816

typedef __attribute__((ext_vector_type(4))) float f32x4;
typedef __attribute__((ext_vector_type(8))) short bf16x8;

// RNE float->bf16, packed pair (a = low 16, b = high 16)
__device__ inline unsigned bf16pk(float a, float b) {
    unsigned ua = __float_as_uint(a), ub = __float_as_uint(b);
    ua = (ua + 0x7FFFu + ((ua >> 16) & 1u)) >> 16;
    ub = (ub + 0x7FFFu + ((ub >> 16) & 1u)) >> 16;
    return ua | (ub << 16);
}

// ---------------------------------------------------------------------------
// Kernel 1: C = E @ [W1top | W1bot] + [b1 | 0]  via bf16 MFMA, f32 accum.
// Grid 16x16 = 256 blocks, 32x32 tile, 4 waves (2x2 of 16x16 mfma tiles),
// full K=768 per block in 3 rounds of KC=256. No split-K, no reduce.
// LDS (bf16, [row][k] 512B pitch, 16B-granule XOR swizzle gi^=(row&7)):
//   Et[32 rows][256 k]   (B-operand: n = E row)
//   Wt[32 cols][256 k]   (A-operand: m = C col; transposed during staging)
// Per wave: 24 mfma, 48 ds_read_b128 total — LDS-issue trivial vs f32 path.
// D layout (m89-verified): lane l, reg p -> row(m)=4*(l>>4)+p, col(n)=l&15.
//   With A=Wt, B=Et: D[m][n] = C[r0+16wr+n][c0+16wc+m].
// ---------------------------------------------------------------------------
__global__ __launch_bounds__(256) void gemm_mfma_kernel(
    const float* __restrict__ E, const float* __restrict__ W1,
    const float* __restrict__ b1, float* __restrict__ C)
{
    __shared__ char lds[2 * 32 * 512];          // Et 16KB + Wt 16KB
    char* EtB = lds;
    char* WtB = lds + 32 * 512;

    const int tid  = threadIdx.x;
    const int r0   = blockIdx.y * 32, c0 = blockIdx.x * 32;
    const int c0w  = c0 & 255;
    const int dofs = (c0 >= 256) ? FD : 0;
    const int lane = tid & 63, wave = tid >> 6;
    const int wr = wave >> 1, wc = wave & 1;
    const int m = lane & 15, g = lane >> 4;
    const int arow = 16 * wc + m;               // Wt row (= local C col)
    const int brow = 16 * wr + m;               // Et row (= local C row)

    f32x4 acc = {0.f, 0.f, 0.f, 0.f};
    const float4* E4 = (const float4*)E;        // row pitch 192 f4

    for (int rnd = 0; rnd < 3; ++rnd) {
        if (rnd) __syncthreads();               // LDS reuse guard

        // ---- stage Et: 32 rows x 256 k, f4 loads + packed b64 writes ----
        #pragma unroll
        for (int s = 0; s < 8; ++s) {
            int idx = tid + s * 256;            // 2048 f4
            int r = idx >> 6, c4 = idx & 63;    // k = 4*c4
            float4 v = E4[(size_t)(r0 + r) * 192 + rnd * 64 + c4];
            uint2 pk;
            pk.x = bf16pk(v.x, v.y);
            pk.y = bf16pk(v.z, v.w);
            int gi = (c4 >> 1) ^ (r & 7);
            *(uint2*)(EtB + r * 512 + gi * 16 + (c4 & 1) * 8) = pk;
        }
        // ---- stage Wt (transpose): c = tid&31, k-pairs via tid>>5 ----
        {
            int c = tid & 31, dp = tid >> 5;
            #pragma unroll
            for (int it = 0; it < 16; ++it) {
                int kp = dp + 8 * it;           // k-pair 0..127
                int d = dofs + rnd * 256 + 2 * kp;
                float w0 = W1[(size_t)d * 256 + c0w + c];
                float w1 = W1[(size_t)(d + 1) * 256 + c0w + c];
                unsigned pk = bf16pk(w0, w1);
                int gi = (kp >> 2) ^ (c & 7);
                *(unsigned*)(WtB + c * 512 + gi * 16 + (kp & 3) * 4) = pk;
            }
        }
        __syncthreads();

        // ---- 8 mfma per wave (K chunk = 256) ----
        #pragma unroll
        for (int ks = 0; ks < 8; ++ks) {
            int giA = (4 * ks + g) ^ (arow & 7);
            int giB = (4 * ks + g) ^ (brow & 7);
            bf16x8 af = *(const bf16x8*)(WtB + arow * 512 + giA * 16);
            bf16x8 bf = *(const bf16x8*)(EtB + brow * 512 + giB * 16);
            acc = __builtin_amdgcn_mfma_f32_16x16x32_bf16(af, bf, acc, 0, 0, 0);
        }
    }

    // ---- epilogue: D lane l reg p -> C[r0+16wr+m? no: row uses n=l&15 ----
    const int row = r0 + 16 * wr + m;           // n = l&15
    const int col = c0 + 16 * wc + 4 * g;       // m = 4*(l>>4)+p
    float4 b = {0.f, 0.f, 0.f, 0.f};
    if (c0 < 256) b = ((const float4*)b1)[col >> 2];
    float4 o = {acc[0] + b.x, acc[1] + b.y, acc[2] + b.z, acc[3] + b.w};
    *(float4*)&C[(size_t)row * NC + col] = o;
}

// ---------------------------------------------------------------------------
// Kernel 2: pair scores. 16x32 pair tile, 272 blocks (all CUs), 1x2 micro.
// LDS: As f4[16][64], Bs f4[32][64], XOR swizzle key (row>>1)&7 (conflict-
// free, verified R6). W2 read from GLOBAL with uniform index -> s_load,
// no LDS instruction. 3 b128 per thread per k4 vs 24 VALU ops.
// ---------------------------------------------------------------------------
__global__ __launch_bounds__(256) void pair_kernel(
    const float* __restrict__ C, const float* __restrict__ W2,
    const float* __restrict__ b2, float* __restrict__ out)
{
    __shared__ float4 As[16 * 64];
    __shared__ float4 Bs[32 * 64];

    // decode (bi: 32 row-tiles of 16, bj: 16 col-tiles of 32), bj >= bi/2
    int rem = blockIdx.x, bi = 0;
    while (rem >= 16 - (bi >> 1)) { rem -= 16 - (bi >> 1); ++bi; }
    const int bj = (bi >> 1) + rem;
    const int i0 = bi * 16, j0 = bj * 32;

    const int tid = threadIdx.x;
    const float4* C4 = (const float4*)C;        // row pitch 128 f4

    #pragma unroll
    for (int s = 0; s < 4; ++s) {               // A: 16 rows x 64 f4
        int idx = tid + 256 * s;
        int row = idx >> 6, c4 = idx & 63;
        As[row * 64 + (c4 ^ ((row >> 1) & 7))] = C4[(i0 + row) * 128 + c4];
    }
    #pragma unroll
    for (int s = 0; s < 8; ++s) {               // B: 32 rows x 64 f4
        int idx = tid + 256 * s;
        int row = idx >> 6, c4 = idx & 63;
        Bs[row * 64 + (c4 ^ ((row >> 1) & 7))] = C4[(j0 + row) * 128 + 64 + c4];
    }
    __syncthreads();

    const int tx = tid & 15, ty = tid >> 4;
    const int keyA = (ty >> 1) & 7, keyB = tx & 7;
    const float4* W24 = (const float4*)W2;

    float acc0 = 0.f, acc1 = 0.f;
    #pragma unroll 8
    for (int k4 = 0; k4 < HD / 4; ++k4) {
        float4 a  = As[ty * 64 + (k4 ^ keyA)];
        float4 b0 = Bs[(2 * tx + 0) * 64 + (k4 ^ keyB)];
        float4 b1v = Bs[(2 * tx + 1) * 64 + (k4 ^ keyB)];
        float4 w = W24[k4];                     // uniform -> s_load
        acc0 = fmaf(fmaxf(a.x + b0.x, 0.f), w.x, acc0);
        acc0 = fmaf(fmaxf(a.y + b0.y, 0.f), w.y, acc0);
        acc0 = fmaf(fmaxf(a.z + b0.z, 0.f), w.z, acc0);
        acc0 = fmaf(fmaxf(a.w + b0.w, 0.f), w.w, acc0);
        acc1 = fmaf(fmaxf(a.x + b1v.x, 0.f), w.x, acc1);
        acc1 = fmaf(fmaxf(a.y + b1v.y, 0.f), w.y, acc1);
        acc1 = fmaf(fmaxf(a.z + b1v.z, 0.f), w.z, acc1);
        acc1 = fmaf(fmaxf(a.w + b1v.w, 0.f), w.w, acc1);
    }

    const float bias2 = b2[0];
    const int i = i0 + ty;
    #pragma unroll
    for (int u = 0; u < 2; ++u) {
        int j = j0 + 2 * tx + u;
        float v = u ? acc1 : acc0;
        if (j > i) {
            int p = i * (2 * NF - i - 1) / 2 + (j - i - 1);
            out[p]             = (float)i;
            out[PAIRS + p]     = (float)j;
            out[2 * PAIRS + p] = v + bias2;
        }
    }
}

extern "C" void kernel_launch(void* const* d_in, const int* in_sizes, int n_in,
                              void* d_out, int out_size, void* d_ws, size_t ws_size,
                              hipStream_t stream) {
    const float* E  = (const float*)d_in[0];
    const float* W1 = (const float*)d_in[1];
    const float* b1 = (const float*)d_in[2];
    const float* W2 = (const float*)d_in[3];
    const float* b2 = (const float*)d_in[4];
    float* out = (float*)d_out;
    float* C   = (float*)d_ws;                  // 1 MiB

    gemm_mfma_kernel<<<dim3(16, 16), 256, 0, stream>>>(E, W1, b1, C);
    pair_kernel<<<272, 256, 0, stream>>>(C, W2, b2, out);
}